// Round 4
// baseline (721.397 us; speedup 1.0000x reference)
//
#include <hip/hip_runtime.h>
#include <math.h>

#define B_ 256
#define S_ 512
#define K_ 20
#define D_ 256
#define NT 512
#define LDH 264   // LDS row stride (shorts), 16B-aligned rows, bank-spread

typedef __attribute__((ext_vector_type(8))) short short8;
typedef __attribute__((ext_vector_type(4))) short short4v;
typedef __attribute__((ext_vector_type(4))) float f32x4;
typedef __attribute__((ext_vector_type(8))) _Float16 half8;
typedef __attribute__((ext_vector_type(2))) __fp16 fp16x2;   // cvt_pkrtz result type
typedef __attribute__((ext_vector_type(2))) unsigned int uint2v;

__device__ __forceinline__ unsigned short rne_bf16(float f) {
  unsigned u = __builtin_bit_cast(unsigned, f);
  u += 0x7FFFu + ((u >> 16) & 1u);
  return (unsigned short)(u >> 16);
}
__device__ __forceinline__ float bf16_to_f32(unsigned short h) {
  return __builtin_bit_cast(float, ((unsigned)h) << 16);
}
__device__ __forceinline__ unsigned pk_f16(float a, float b) {
  fp16x2 p = __builtin_amdgcn_cvt_pkrtz(a, b);  // v_cvt_pkrtz_f16_f32
  return __builtin_bit_cast(unsigned, p);
}

// rnn_fused10: per-lane lam/g (no ds_bpermute), masked ke=1 B reads (zero
// rows never read), packed RTZ f16 state stores, per-lane final emit.
__global__ __launch_bounds__(NT, 2)
void rnn_fused10(const float* __restrict__ es, const int* __restrict__ mask,
                 const float* __restrict__ keys, const float* __restrict__ U,
                 const float* __restrict__ V, const float* __restrict__ W,
                 float* __restrict__ XWc, float* __restrict__ out) {
  __shared__ unsigned short sH0[32 * LDH];  // state buf 0 (prologue: hi staging)
  __shared__ unsigned short sH1[32 * LDH];  // state buf 1 (prologue: lo staging)
  __shared__ float sRed[2][3][32][12];      // [buf][psq/pxh/pxk][k-row][wave 0..7 + pad]
  __shared__ short sAct[S_];
  __shared__ int   sNact;

  const int b = blockIdx.x, t = threadIdx.x;
  const int w = t >> 6, lane = t & 63, quad = lane >> 4, n = lane & 15;
  const int e0a = (w << 5) + quad * 4;

  // ---- P0: zero sRed (rows 20..31 stay 0 forever); compact active list ----
  for (int i = t; i < 2 * 3 * 32 * 12; i += NT) ((float*)sRed)[i] = 0.0f;
  if (w == 0) {
    int base = 0;
    for (int c = 0; c < 8; ++c) {
      int s = c * 64 + lane;
      int mv = mask[b * S_ + s];
      unsigned long long bal = __ballot(mv != 0);
      int pos = base + (int)__popcll(bal & ((1ull << lane) - 1ull));
      if (mv) sAct[pos] = (short)s;
      base += (int)__popcll(bal);
    }
    if (lane == 0) sNact = base;
  }
  __syncthreads();
  const int nAct = sNact;

  short8 aHi[8][2], aLo[8][2];  // split-bf16 A-frags (W, then V)
  auto load_A = [&](const float* __restrict__ M) {
#pragma unroll
    for (int kt = 0; kt < 8; ++kt)
#pragma unroll
      for (int et = 0; et < 2; ++et) {
        const int e = ((2 * w + et) << 4) + n;
        const int d0 = kt * 32 + quad * 8;
        short8 h8, l8;
#pragma unroll
        for (int j = 0; j < 8; ++j) {
          float f = M[(d0 + j) * D_ + e];
          unsigned short hi = rne_bf16(f);
          h8[j] = (short)hi;
          l8[j] = (short)rne_bf16(f - bf16_to_f32(hi));
        }
        aHi[kt][et] = h8; aLo[kt][et] = l8;
      }
  };
  auto run_mfma3 = [&](f32x4 acc[2][2]) {  // split-bf16 3-product (hi sH0, lo sH1)
#pragma unroll
    for (int kt = 0; kt < 8; ++kt) {
      short8 bhi[2], blo[2];
#pragma unroll
      for (int ke = 0; ke < 2; ++ke) {
        const int off = (ke * 16 + n) * LDH + kt * 32 + quad * 8;
        bhi[ke] = *(const short8*)&sH0[off];
        blo[ke] = *(const short8*)&sH1[off];
      }
#pragma unroll
      for (int et = 0; et < 2; ++et)
#pragma unroll
        for (int ke = 0; ke < 2; ++ke) {
          acc[et][ke] = __builtin_amdgcn_mfma_f32_16x16x32_bf16(aHi[kt][et], bhi[ke], acc[et][ke], 0, 0, 0);
          acc[et][ke] = __builtin_amdgcn_mfma_f32_16x16x32_bf16(aLo[kt][et], bhi[ke], acc[et][ke], 0, 0, 0);
          acc[et][ke] = __builtin_amdgcn_mfma_f32_16x16x32_bf16(aHi[kt][et], blo[ke], acc[et][ke], 0, 0, 0);
        }
    }
  };

  // ---- Phase XW: compact x@W for this batch's active rows -> scratch ----
  const size_t bbase = (size_t)b * S_;
  if (nAct > 0) {
    load_A(W);
    const int nPass = (nAct + 31) >> 5;
    for (int p = 0; p < nPass; ++p) {
      {  // stage 32 gathered es rows, split-bf16
        const int rr = t >> 4, c0 = (t & 15) * 16;
        const int ridx = p * 32 + rr;
        const int sidx = sAct[(ridx < nAct) ? ridx : (nAct - 1)];
        const float* src = es + ((size_t)b * S_ + sidx) * D_ + c0;
#pragma unroll
        for (int h2 = 0; h2 < 2; ++h2) {
          f32x4 f0 = *(const f32x4*)(src + h2 * 8);
          f32x4 f1 = *(const f32x4*)(src + h2 * 8 + 4);
          short8 hh, ll;
#pragma unroll
          for (int j = 0; j < 4; ++j) {
            unsigned short a = rne_bf16(f0[j]);
            hh[j] = (short)a; ll[j] = (short)rne_bf16(f0[j] - bf16_to_f32(a));
            unsigned short bq = rne_bf16(f1[j]);
            hh[4 + j] = (short)bq; ll[4 + j] = (short)rne_bf16(f1[j] - bf16_to_f32(bq));
          }
          *(short8*)&sH0[rr * LDH + c0 + h2 * 8] = hh;
          *(short8*)&sH1[rr * LDH + c0 + h2 * 8] = ll;
        }
      }
      __syncthreads();
      f32x4 acc[2][2] = {};
      run_mfma3(acc);
#pragma unroll
      for (int et = 0; et < 2; ++et)
#pragma unroll
        for (int ke = 0; ke < 2; ++ke) {
          const int g = p * 32 + ke * 16 + n;
          if (g < nAct)
            *(f32x4*)&XWc[(bbase + g) * D_ + e0a + 16 * et] = acc[et][ke];
        }
      __syncthreads();
    }
  }

  // ---- zero BOTH buffers fully (rows 20..31 + pads stay 0 afterwards) ----
  for (int i = t; i < 32 * LDH; i += NT) { sH0[i] = 0; sH1[i] = 0; }
  __syncthreads();

  // ---- keys staging (split-bf16) + kReg + V frags ----
  for (int i = t; i < K_ * D_; i += NT) {
    int k = i >> 8, d = i & 255;
    float f = keys[(b * K_ + k) * D_ + d];
    unsigned short hi = rne_bf16(f);
    sH0[k * LDH + d] = hi;
    sH1[k * LDH + d] = rne_bf16(f - bf16_to_f32(hi));
  }
  f32x4 kReg[2][2];
#pragma unroll
  for (int et = 0; et < 2; ++et)
#pragma unroll
    for (int ke = 0; ke < 2; ++ke) {
      const int k = ke * 16 + n;
#pragma unroll
      for (int r = 0; r < 4; ++r)
        kReg[et][ke][r] = (k < K_) ? keys[(size_t)(b * K_ + k) * D_ + e0a + 16 * et + r] : 0.0f;
    }
  load_A(V);
  __syncthreads();

  f32x4 kvReg[2][2] = {};
  run_mfma3(kvReg);
  __syncthreads();  // kV reads done

  // ---- zero state rows (both buffers); load U as fp16 frags ----
  for (int i = t; i < K_ * LDH; i += NT) { sH0[i] = 0; sH1[i] = 0; }
  short8 aU[8][2];  // fp16 U^T frags (single product in the loop)
#pragma unroll
  for (int kt = 0; kt < 8; ++kt)
#pragma unroll
    for (int et = 0; et < 2; ++et) {
      const int e = ((2 * w + et) << 4) + n;
      const int d0 = kt * 32 + quad * 8;
      short8 h8;
#pragma unroll
      for (int j = 0; j < 8; ++j)
        h8[j] = (short)__builtin_bit_cast(unsigned short, (_Float16)U[(d0 + j) * D_ + e]);
      aU[kt][et] = h8;
    }
  // fp16 MFMA; ke=1 B rows 20..31 are permanently zero -> only n<4 lanes read.
  auto run_mfma1 = [&](f32x4 acc[2][2], const unsigned short* __restrict__ bp) {
#pragma unroll
    for (int kt = 0; kt < 8; ++kt) {
      const int co = kt * 32 + quad * 8;
      short8 b0 = *(const short8*)&bp[n * LDH + co];
      short8 b1 = {};
      if (n < 4) b1 = *(const short8*)&bp[(16 + n) * LDH + co];
      half8 q0 = __builtin_bit_cast(half8, b0);
      half8 q1 = __builtin_bit_cast(half8, b1);
#pragma unroll
      for (int et = 0; et < 2; ++et) {
        half8 aq = __builtin_bit_cast(half8, aU[kt][et]);
        acc[et][0] = __builtin_amdgcn_mfma_f32_16x16x32_f16(aq, q0, acc[et][0], 0, 0, 0);
        acc[et][1] = __builtin_amdgcn_mfma_f32_16x16x32_f16(aq, q1, acc[et][1], 0, 0, 0);
      }
    }
  };

  f32x4 hReg[2][2] = {};
  f32x4 xEc[2] = {}, xwEc[2] = {};
  if (nAct > 0) {
    const int s1 = sAct[(nAct > 1) ? 1 : 0];
#pragma unroll
    for (int et = 0; et < 2; ++et) {
      xEc[et]  = *(const f32x4*)&es[((size_t)b * S_ + s1) * D_ + e0a + 16 * et];
      xwEc[et] = *(const f32x4*)&XWc[bbase * D_ + e0a + 16 * et];
    }
    // pxk seed for step 0: x_0 . keys
    const int s0 = sAct[0];
    float p0 = 0.0f, p1 = 0.0f;
#pragma unroll
    for (int et = 0; et < 2; ++et) {
      f32x4 xq = *(const f32x4*)&es[((size_t)b * S_ + s0) * D_ + e0a + 16 * et];
#pragma unroll
      for (int r = 0; r < 4; ++r) {
        p0 = fmaf(xq[r], kReg[et][0][r], p0);
        p1 = fmaf(xq[r], kReg[et][1][r], p1);
      }
    }
    p0 += __shfl_xor(p0, 16, 64); p0 += __shfl_xor(p0, 32, 64);
    p1 += __shfl_xor(p1, 16, 64); p1 += __shfl_xor(p1, 32, 64);
    if (quad == 0) {
      sRed[0][2][n][w] = p0;
      if (n < 4) sRed[0][2][16 + n][w] = p1;
    }
  }
  __syncthreads();  // ready for step 0

  // cross-half swap on VALU pipe
  auto xswap = [](float& a, float& b) {
    asm("v_permlane32_swap_b32 %0, %1" : "+v"(a), "+v"(b));
  };

  // ---- recurrence: one barrier per step ----
  for (int i = 0; i < nAct; ++i) {
    const int rb = i & 1, wbuf = rb ^ 1;
    const unsigned short* bR = rb ? sH1 : sH0;
    unsigned short* bW = rb ? sH0 : sH1;

    // next-slot global loads (consumed in epilogue of step i+1)
    const int iX = (i + 2 < nAct) ? i + 2 : nAct - 1;
    const int iW = (i + 1 < nAct) ? i + 1 : nAct - 1;
    const size_t rX = ((size_t)b * S_ + sAct[iX]) * D_;
    f32x4 xEn[2], xwEn[2];
#pragma unroll
    for (int et = 0; et < 2; ++et) {
      xEn[et]  = *(const f32x4*)&es[rX + e0a + 16 * et];
      xwEn[et] = *(const f32x4*)&XWc[(bbase + iW) * D_ + e0a + 16 * et];
    }

    // per-lane lam/g from previous step's partials: k0 = n; k1 = 16+n (n<4)
    float lm0, g0, lm1 = 0.0f, g1 = 0.0f;
    {
      f32x4 qa = *(const f32x4*)&sRed[rb][0][n][0];
      f32x4 qb = *(const f32x4*)&sRed[rb][0][n][4];
      f32x4 ha = *(const f32x4*)&sRed[rb][1][n][0];
      f32x4 hb = *(const f32x4*)&sRed[rb][1][n][4];
      f32x4 ka = *(const f32x4*)&sRed[rb][2][n][0];
      f32x4 kb = *(const f32x4*)&sRed[rb][2][n][4];
      f32x4 qs = qa + qb, hs = ha + hb, ks = ka + kb;
      float ss = (qs[0] + qs[1]) + (qs[2] + qs[3]);
      float xh = (hs[0] + hs[1]) + (hs[2] + hs[3]);
      float xk = (ks[0] + ks[1]) + (ks[2] + ks[3]);
      lm0 = rsqrtf(fmaxf(ss, 1e-12f));
      g0 = __fdividef(1.0f, 1.0f + __expf(-fmaf(lm0, xh, xk)));
    }
    if (n < 4) {
      const int k2 = 16 + n;
      f32x4 qa = *(const f32x4*)&sRed[rb][0][k2][0];
      f32x4 qb = *(const f32x4*)&sRed[rb][0][k2][4];
      f32x4 ha = *(const f32x4*)&sRed[rb][1][k2][0];
      f32x4 hb = *(const f32x4*)&sRed[rb][1][k2][4];
      f32x4 ka = *(const f32x4*)&sRed[rb][2][k2][0];
      f32x4 kb = *(const f32x4*)&sRed[rb][2][k2][4];
      f32x4 qs = qa + qb, hs = ha + hb, ks = ka + kb;
      float ss = (qs[0] + qs[1]) + (qs[2] + qs[3]);
      float xh = (hs[0] + hs[1]) + (hs[2] + hs[3]);
      float xk = (ks[0] + ks[1]) + (ks[2] + ks[3]);
      lm1 = rsqrtf(fmaxf(ss, 1e-12f));
      g1 = __fdividef(1.0f, 1.0f + __expf(-fmaf(lm1, xh, xk)));
    }

    f32x4 acc[2][2] = {};
    run_mfma1(acc, bR);

    float psq0 = 0.0f, psq1 = 0.0f, pxh0 = 0.0f, pxh1 = 0.0f, pxk0 = 0.0f, pxk1 = 0.0f;
#pragma unroll
    for (int et = 0; et < 2; ++et) {
      const int e0 = e0a + 16 * et;
      f32x4 xw4 = xwEc[et];
      f32x4 xn4 = xEc[et];
      {  // ke=0
        f32x4 u;
#pragma unroll
        for (int r = 0; r < 4; ++r) {
          float T = fmaxf(fmaf(lm0, acc[et][0][r], kvReg[et][0][r] + xw4[r]), 0.0f);
          float uv = fmaf(g0, T, lm0 * hReg[et][0][r]);
          u[r] = uv;
          psq0 = fmaf(uv, uv, psq0);
          pxh0 = fmaf(xn4[r], uv, pxh0);
          pxk0 = fmaf(xn4[r], kReg[et][0][r], pxk0);
        }
        hReg[et][0] = u;
        uint2v hh;
        hh[0] = pk_f16(u[0], u[1]);
        hh[1] = pk_f16(u[2], u[3]);
        *(uint2v*)&bW[n * LDH + e0] = hh;
      }
      {  // ke=1
        f32x4 u;
#pragma unroll
        for (int r = 0; r < 4; ++r) {
          float T = fmaxf(fmaf(lm1, acc[et][1][r], kvReg[et][1][r] + xw4[r]), 0.0f);
          float uv = fmaf(g1, T, lm1 * hReg[et][1][r]);
          u[r] = uv;
          psq1 = fmaf(uv, uv, psq1);
          pxh1 = fmaf(xn4[r], uv, pxh1);
          pxk1 = fmaf(xn4[r], kReg[et][1][r], pxk1);
        }
        hReg[et][1] = u;
        if (n < 4) {
          uint2v hh;
          hh[0] = pk_f16(u[0], u[1]);
          hh[1] = pk_f16(u[2], u[3]);
          *(uint2v*)&bW[(16 + n) * LDH + e0] = hh;
        }
      }
    }
    // quad-pair reduce (LDS swizzle) + cross-half on VALU via permlane swap
    psq0 += __shfl_xor(psq0, 16, 64); psq1 += __shfl_xor(psq1, 16, 64);
    pxh0 += __shfl_xor(pxh0, 16, 64); pxh1 += __shfl_xor(pxh1, 16, 64);
    pxk0 += __shfl_xor(pxk0, 16, 64); pxk1 += __shfl_xor(pxk1, 16, 64);
    xswap(psq0, psq1); const float sq_s = psq0 + psq1;
    xswap(pxh0, pxh1); const float xh_s = pxh0 + pxh1;
    xswap(pxk0, pxk1); const float xk_s = pxk0 + pxk1;
    if (quad == 0) {  // lanes 0..15: totals for k = n
      sRed[wbuf][0][n][w] = sq_s; sRed[wbuf][1][n][w] = xh_s; sRed[wbuf][2][n][w] = xk_s;
    }
    if (quad == 2 && n < 4) {  // lanes 32..35: totals for k = 16+n
      sRed[wbuf][0][16 + n][w] = sq_s; sRed[wbuf][1][16 + n][w] = xh_s; sRed[wbuf][2][16 + n][w] = xk_s;
    }
#pragma unroll
    for (int et = 0; et < 2; ++et) { xEc[et] = xEn[et]; xwEc[et] = xwEn[et]; }
    __syncthreads();  // the only per-step barrier
  }

  // ---- final lam (per-lane) + emit ----
  const int fb = nAct & 1;
  float lmF0, lmF1 = 0.0f;
  {
    f32x4 qa = *(const f32x4*)&sRed[fb][0][n][0];
    f32x4 qb = *(const f32x4*)&sRed[fb][0][n][4];
    f32x4 qs = qa + qb;
    lmF0 = rsqrtf(fmaxf((qs[0] + qs[1]) + (qs[2] + qs[3]), 1e-12f));
  }
  if (n < 4) {
    f32x4 qa = *(const f32x4*)&sRed[fb][0][16 + n][0];
    f32x4 qb = *(const f32x4*)&sRed[fb][0][16 + n][4];
    f32x4 qs = qa + qb;
    lmF1 = rsqrtf(fmaxf((qs[0] + qs[1]) + (qs[2] + qs[3]), 1e-12f));
  }
#pragma unroll
  for (int et = 0; et < 2; ++et) {
    const int e0 = e0a + 16 * et;
    {
      f32x4 o;
#pragma unroll
      for (int r = 0; r < 4; ++r) o[r] = lmF0 * hReg[et][0][r];
      *(f32x4*)&out[(size_t)(b * K_ + n) * D_ + e0] = o;
    }
    if (n < 4) {
      f32x4 o;
#pragma unroll
      for (int r = 0; r < 4; ++r) o[r] = lmF1 * hReg[et][1][r];
      *(f32x4*)&out[(size_t)(b * K_ + 16 + n) * D_ + e0] = o;
    }
  }
}

extern "C" void kernel_launch(void* const* d_in, const int* in_sizes, int n_in,
                              void* d_out, int out_size, void* d_ws, size_t ws_size,
                              hipStream_t stream) {
  const float* es   = (const float*)d_in[0];
  const int*   mask = (const int*)d_in[1];
  const float* keys = (const float*)d_in[2];
  const float* U    = (const float*)d_in[3];
  const float* V    = (const float*)d_in[4];
  const float* W    = (const float*)d_in[5];
  float* out = (float*)d_out;
  float* XWc = (float*)d_ws;  // compact per-block XW: 256 x 512 x 1KB = 128 MiB
  rnn_fused10<<<B_, NT, 0, stream>>>(es, mask, keys, U, V, W, XWc, out);
}

// Round 5
// 683.899 us; speedup vs baseline: 1.0548x; 1.0548x over previous
//
#include <hip/hip_runtime.h>
#include <math.h>

#define B_ 256
#define S_ 512
#define K_ 20
#define D_ 256
#define NT 512
#define LDH 264   // LDS row stride (shorts), 16B-aligned rows, bank-spread

typedef __attribute__((ext_vector_type(8))) short short8;
typedef __attribute__((ext_vector_type(4))) short short4v;
typedef __attribute__((ext_vector_type(4))) float f32x4;
typedef __attribute__((ext_vector_type(8))) _Float16 half8;
typedef __attribute__((ext_vector_type(2))) __fp16 fp16x2;   // cvt_pkrtz result type
typedef __attribute__((ext_vector_type(2))) unsigned int uint2v;

__device__ __forceinline__ unsigned short rne_bf16(float f) {
  unsigned u = __builtin_bit_cast(unsigned, f);
  u += 0x7FFFu + ((u >> 16) & 1u);
  return (unsigned short)(u >> 16);
}
__device__ __forceinline__ float bf16_to_f32(unsigned short h) {
  return __builtin_bit_cast(float, ((unsigned)h) << 16);
}
__device__ __forceinline__ unsigned pk_f16(float a, float b) {
  fp16x2 p = __builtin_amdgcn_cvt_pkrtz(a, b);  // v_cvt_pkrtz_f16_f32
  return __builtin_bit_cast(unsigned, p);
}

// rnn_fused11: single-stream per-lane lam/g (k = lane&31) + 4 static
// ds_swizzle broadcasts (replaces R4's double stream / R2's ds_bpermute).
// Masked ke=1 B reads, packed RTZ f16 state stores, per-lane final emit.
__global__ __launch_bounds__(NT, 2)
void rnn_fused11(const float* __restrict__ es, const int* __restrict__ mask,
                 const float* __restrict__ keys, const float* __restrict__ U,
                 const float* __restrict__ V, const float* __restrict__ W,
                 float* __restrict__ XWc, float* __restrict__ out) {
  __shared__ unsigned short sH0[32 * LDH];  // state buf 0 (prologue: hi staging)
  __shared__ unsigned short sH1[32 * LDH];  // state buf 1 (prologue: lo staging)
  __shared__ float sRed[2][3][32][12];      // [buf][psq/pxh/pxk][k-row][wave + pad]
  __shared__ short sAct[S_];
  __shared__ int   sNact;

  const int b = blockIdx.x, t = threadIdx.x;
  const int w = t >> 6, lane = t & 63, quad = lane >> 4, n = lane & 15;
  const int e0a = (w << 5) + quad * 4;

  // ---- P0: zero sRed (rows 20..31 stay 0 forever); compact active list ----
  for (int i = t; i < 2 * 3 * 32 * 12; i += NT) ((float*)sRed)[i] = 0.0f;
  if (w == 0) {
    int base = 0;
    for (int c = 0; c < 8; ++c) {
      int s = c * 64 + lane;
      int mv = mask[b * S_ + s];
      unsigned long long bal = __ballot(mv != 0);
      int pos = base + (int)__popcll(bal & ((1ull << lane) - 1ull));
      if (mv) sAct[pos] = (short)s;
      base += (int)__popcll(bal);
    }
    if (lane == 0) sNact = base;
  }
  __syncthreads();
  const int nAct = sNact;

  short8 aHi[8][2], aLo[8][2];  // split-bf16 A-frags (W, then V)
  auto load_A = [&](const float* __restrict__ M) {
#pragma unroll
    for (int kt = 0; kt < 8; ++kt)
#pragma unroll
      for (int et = 0; et < 2; ++et) {
        const int e = ((2 * w + et) << 4) + n;
        const int d0 = kt * 32 + quad * 8;
        short8 h8, l8;
#pragma unroll
        for (int j = 0; j < 8; ++j) {
          float f = M[(d0 + j) * D_ + e];
          unsigned short hi = rne_bf16(f);
          h8[j] = (short)hi;
          l8[j] = (short)rne_bf16(f - bf16_to_f32(hi));
        }
        aHi[kt][et] = h8; aLo[kt][et] = l8;
      }
  };
  auto run_mfma3 = [&](f32x4 acc[2][2]) {  // split-bf16 3-product (hi sH0, lo sH1)
#pragma unroll
    for (int kt = 0; kt < 8; ++kt) {
      short8 bhi[2], blo[2];
#pragma unroll
      for (int ke = 0; ke < 2; ++ke) {
        const int off = (ke * 16 + n) * LDH + kt * 32 + quad * 8;
        bhi[ke] = *(const short8*)&sH0[off];
        blo[ke] = *(const short8*)&sH1[off];
      }
#pragma unroll
      for (int et = 0; et < 2; ++et)
#pragma unroll
        for (int ke = 0; ke < 2; ++ke) {
          acc[et][ke] = __builtin_amdgcn_mfma_f32_16x16x32_bf16(aHi[kt][et], bhi[ke], acc[et][ke], 0, 0, 0);
          acc[et][ke] = __builtin_amdgcn_mfma_f32_16x16x32_bf16(aLo[kt][et], bhi[ke], acc[et][ke], 0, 0, 0);
          acc[et][ke] = __builtin_amdgcn_mfma_f32_16x16x32_bf16(aHi[kt][et], blo[ke], acc[et][ke], 0, 0, 0);
        }
    }
  };

  // ---- Phase XW: compact x@W for this batch's active rows -> scratch ----
  const size_t bbase = (size_t)b * S_;
  if (nAct > 0) {
    load_A(W);
    const int nPass = (nAct + 31) >> 5;
    for (int p = 0; p < nPass; ++p) {
      {  // stage 32 gathered es rows, split-bf16
        const int rr = t >> 4, c0 = (t & 15) * 16;
        const int ridx = p * 32 + rr;
        const int sidx = sAct[(ridx < nAct) ? ridx : (nAct - 1)];
        const float* src = es + ((size_t)b * S_ + sidx) * D_ + c0;
#pragma unroll
        for (int h2 = 0; h2 < 2; ++h2) {
          f32x4 f0 = *(const f32x4*)(src + h2 * 8);
          f32x4 f1 = *(const f32x4*)(src + h2 * 8 + 4);
          short8 hh, ll;
#pragma unroll
          for (int j = 0; j < 4; ++j) {
            unsigned short a = rne_bf16(f0[j]);
            hh[j] = (short)a; ll[j] = (short)rne_bf16(f0[j] - bf16_to_f32(a));
            unsigned short bq = rne_bf16(f1[j]);
            hh[4 + j] = (short)bq; ll[4 + j] = (short)rne_bf16(f1[j] - bf16_to_f32(bq));
          }
          *(short8*)&sH0[rr * LDH + c0 + h2 * 8] = hh;
          *(short8*)&sH1[rr * LDH + c0 + h2 * 8] = ll;
        }
      }
      __syncthreads();
      f32x4 acc[2][2] = {};
      run_mfma3(acc);
#pragma unroll
      for (int et = 0; et < 2; ++et)
#pragma unroll
        for (int ke = 0; ke < 2; ++ke) {
          const int g = p * 32 + ke * 16 + n;
          if (g < nAct)
            *(f32x4*)&XWc[(bbase + g) * D_ + e0a + 16 * et] = acc[et][ke];
        }
      __syncthreads();
    }
  }

  // ---- zero BOTH buffers fully (rows 20..31 + pads stay 0 afterwards) ----
  for (int i = t; i < 32 * LDH; i += NT) { sH0[i] = 0; sH1[i] = 0; }
  __syncthreads();

  // ---- keys staging (split-bf16) + kReg + V frags ----
  for (int i = t; i < K_ * D_; i += NT) {
    int k = i >> 8, d = i & 255;
    float f = keys[(b * K_ + k) * D_ + d];
    unsigned short hi = rne_bf16(f);
    sH0[k * LDH + d] = hi;
    sH1[k * LDH + d] = rne_bf16(f - bf16_to_f32(hi));
  }
  f32x4 kReg[2][2];
#pragma unroll
  for (int et = 0; et < 2; ++et)
#pragma unroll
    for (int ke = 0; ke < 2; ++ke) {
      const int k = ke * 16 + n;
#pragma unroll
      for (int r = 0; r < 4; ++r)
        kReg[et][ke][r] = (k < K_) ? keys[(size_t)(b * K_ + k) * D_ + e0a + 16 * et + r] : 0.0f;
    }
  load_A(V);
  __syncthreads();

  f32x4 kvReg[2][2] = {};
  run_mfma3(kvReg);
  __syncthreads();  // kV reads done

  // ---- zero state rows (both buffers); load U as fp16 frags ----
  for (int i = t; i < K_ * LDH; i += NT) { sH0[i] = 0; sH1[i] = 0; }
  short8 aU[8][2];  // fp16 U^T frags (single product in the loop)
#pragma unroll
  for (int kt = 0; kt < 8; ++kt)
#pragma unroll
    for (int et = 0; et < 2; ++et) {
      const int e = ((2 * w + et) << 4) + n;
      const int d0 = kt * 32 + quad * 8;
      short8 h8;
#pragma unroll
      for (int j = 0; j < 8; ++j)
        h8[j] = (short)__builtin_bit_cast(unsigned short, (_Float16)U[(d0 + j) * D_ + e]);
      aU[kt][et] = h8;
    }
  // fp16 MFMA; ke=1 B rows 20..31 are permanently zero -> only n<4 lanes read.
  auto run_mfma1 = [&](f32x4 acc[2][2], const unsigned short* __restrict__ bp) {
#pragma unroll
    for (int kt = 0; kt < 8; ++kt) {
      const int co = kt * 32 + quad * 8;
      short8 b0 = *(const short8*)&bp[n * LDH + co];
      short8 b1 = {};
      if (n < 4) b1 = *(const short8*)&bp[(16 + n) * LDH + co];
      half8 q0 = __builtin_bit_cast(half8, b0);
      half8 q1 = __builtin_bit_cast(half8, b1);
#pragma unroll
      for (int et = 0; et < 2; ++et) {
        half8 aq = __builtin_bit_cast(half8, aU[kt][et]);
        acc[et][0] = __builtin_amdgcn_mfma_f32_16x16x32_f16(aq, q0, acc[et][0], 0, 0, 0);
        acc[et][1] = __builtin_amdgcn_mfma_f32_16x16x32_f16(aq, q1, acc[et][1], 0, 0, 0);
      }
    }
  };

  f32x4 hReg[2][2] = {};
  f32x4 xEc[2] = {}, xwEc[2] = {};
  if (nAct > 0) {
    const int s1 = sAct[(nAct > 1) ? 1 : 0];
#pragma unroll
    for (int et = 0; et < 2; ++et) {
      xEc[et]  = *(const f32x4*)&es[((size_t)b * S_ + s1) * D_ + e0a + 16 * et];
      xwEc[et] = *(const f32x4*)&XWc[bbase * D_ + e0a + 16 * et];
    }
    // pxk seed for step 0: x_0 . keys
    const int s0 = sAct[0];
    float p0 = 0.0f, p1 = 0.0f;
#pragma unroll
    for (int et = 0; et < 2; ++et) {
      f32x4 xq = *(const f32x4*)&es[((size_t)b * S_ + s0) * D_ + e0a + 16 * et];
#pragma unroll
      for (int r = 0; r < 4; ++r) {
        p0 = fmaf(xq[r], kReg[et][0][r], p0);
        p1 = fmaf(xq[r], kReg[et][1][r], p1);
      }
    }
    p0 += __shfl_xor(p0, 16, 64); p0 += __shfl_xor(p0, 32, 64);
    p1 += __shfl_xor(p1, 16, 64); p1 += __shfl_xor(p1, 32, 64);
    if (quad == 0) {
      sRed[0][2][n][w] = p0;
      if (n < 4) sRed[0][2][16 + n][w] = p1;
    }
  }
  __syncthreads();  // ready for step 0

  // cross-half swap on VALU pipe
  auto xswap = [](float& a, float& b) {
    asm("v_permlane32_swap_b32 %0, %1" : "+v"(a), "+v"(b));
  };

  // ---- recurrence: one barrier per step ----
  for (int i = 0; i < nAct; ++i) {
    const int rb = i & 1, wbuf = rb ^ 1;
    const unsigned short* bR = rb ? sH1 : sH0;
    unsigned short* bW = rb ? sH0 : sH1;

    // next-slot global loads (consumed in epilogue of step i+1)
    const int iX = (i + 2 < nAct) ? i + 2 : nAct - 1;
    const int iW = (i + 1 < nAct) ? i + 1 : nAct - 1;
    const size_t rX = ((size_t)b * S_ + sAct[iX]) * D_;
    f32x4 xEn[2], xwEn[2];
#pragma unroll
    for (int et = 0; et < 2; ++et) {
      xEn[et]  = *(const f32x4*)&es[rX + e0a + 16 * et];
      xwEn[et] = *(const f32x4*)&XWc[(bbase + iW) * D_ + e0a + 16 * et];
    }

    // single-stream per-lane lam/g: lane computes k = lane&31.
    // rows 20..31 of sRed are zero -> ss=0 -> lm=1e6, g=0.5 (finite, never used)
    float lmv, gv;
    {
      const int kk = lane & 31;
      f32x4 qa = *(const f32x4*)&sRed[rb][0][kk][0];
      f32x4 qb = *(const f32x4*)&sRed[rb][0][kk][4];
      f32x4 ha = *(const f32x4*)&sRed[rb][1][kk][0];
      f32x4 hb = *(const f32x4*)&sRed[rb][1][kk][4];
      f32x4 ka = *(const f32x4*)&sRed[rb][2][kk][0];
      f32x4 kb = *(const f32x4*)&sRed[rb][2][kk][4];
      f32x4 qs = qa + qb, hs = ha + hb, ks = ka + kb;
      float ss = (qs[0] + qs[1]) + (qs[2] + qs[3]);
      float xh = (hs[0] + hs[1]) + (hs[2] + hs[3]);
      float xk = (ks[0] + ks[1]) + (ks[2] + ks[3]);
      lmv = rsqrtf(fmaxf(ss, 1e-12f));
      gv = __fdividef(1.0f, 1.0f + __expf(-fmaf(lmv, xh, xk)));
    }
    // static swizzle broadcasts (pull within each 32-half):
    //   0x000F: lane <- lane&15      (lm/g for k=n, valid: source holds k=n)
    //   0x0203: lane <- 16|(lane&3)  (lm/g for k=16+n at n<4)
    const float lm0 = __builtin_bit_cast(float, __builtin_amdgcn_ds_swizzle(__builtin_bit_cast(int, lmv), 0x000F));
    const float g0  = __builtin_bit_cast(float, __builtin_amdgcn_ds_swizzle(__builtin_bit_cast(int, gv),  0x000F));
    const float lm1s = __builtin_bit_cast(float, __builtin_amdgcn_ds_swizzle(__builtin_bit_cast(int, lmv), 0x0203));
    const float g1s  = __builtin_bit_cast(float, __builtin_amdgcn_ds_swizzle(__builtin_bit_cast(int, gv),  0x0203));
    // zero on n>=4: keeps ke=1 dead lanes' u == 0 (garbage containment)
    const float lm1 = (n < 4) ? lm1s : 0.0f;
    const float g1 = (n < 4) ? g1s : 0.0f;

    f32x4 acc[2][2] = {};
    run_mfma1(acc, bR);

    float psq0 = 0.0f, psq1 = 0.0f, pxh0 = 0.0f, pxh1 = 0.0f, pxk0 = 0.0f, pxk1 = 0.0f;
#pragma unroll
    for (int et = 0; et < 2; ++et) {
      const int e0 = e0a + 16 * et;
      f32x4 xw4 = xwEc[et];
      f32x4 xn4 = xEc[et];
      {  // ke=0
        f32x4 u;
#pragma unroll
        for (int r = 0; r < 4; ++r) {
          float T = fmaxf(fmaf(lm0, acc[et][0][r], kvReg[et][0][r] + xw4[r]), 0.0f);
          float uv = fmaf(g0, T, lm0 * hReg[et][0][r]);
          u[r] = uv;
          psq0 = fmaf(uv, uv, psq0);
          pxh0 = fmaf(xn4[r], uv, pxh0);
          pxk0 = fmaf(xn4[r], kReg[et][0][r], pxk0);
        }
        hReg[et][0] = u;
        uint2v hh;
        hh[0] = pk_f16(u[0], u[1]);
        hh[1] = pk_f16(u[2], u[3]);
        *(uint2v*)&bW[n * LDH + e0] = hh;
      }
      {  // ke=1
        f32x4 u;
#pragma unroll
        for (int r = 0; r < 4; ++r) {
          float T = fmaxf(fmaf(lm1, acc[et][1][r], kvReg[et][1][r] + xw4[r]), 0.0f);
          float uv = fmaf(g1, T, lm1 * hReg[et][1][r]);
          u[r] = uv;
          psq1 = fmaf(uv, uv, psq1);
          pxh1 = fmaf(xn4[r], uv, pxh1);
          pxk1 = fmaf(xn4[r], kReg[et][1][r], pxk1);
        }
        hReg[et][1] = u;
        if (n < 4) {
          uint2v hh;
          hh[0] = pk_f16(u[0], u[1]);
          hh[1] = pk_f16(u[2], u[3]);
          *(uint2v*)&bW[(16 + n) * LDH + e0] = hh;
        }
      }
    }
    // quad-pair reduce (LDS swizzle) + cross-half on VALU via permlane swap
    psq0 += __shfl_xor(psq0, 16, 64); psq1 += __shfl_xor(psq1, 16, 64);
    pxh0 += __shfl_xor(pxh0, 16, 64); pxh1 += __shfl_xor(pxh1, 16, 64);
    pxk0 += __shfl_xor(pxk0, 16, 64); pxk1 += __shfl_xor(pxk1, 16, 64);
    xswap(psq0, psq1); const float sq_s = psq0 + psq1;
    xswap(pxh0, pxh1); const float xh_s = pxh0 + pxh1;
    xswap(pxk0, pxk1); const float xk_s = pxk0 + pxk1;
    if (quad == 0) {  // lanes 0..15: totals for k = n
      sRed[wbuf][0][n][w] = sq_s; sRed[wbuf][1][n][w] = xh_s; sRed[wbuf][2][n][w] = xk_s;
    }
    if (quad == 2 && n < 4) {  // lanes 32..35: totals for k = 16+n
      sRed[wbuf][0][16 + n][w] = sq_s; sRed[wbuf][1][16 + n][w] = xh_s; sRed[wbuf][2][16 + n][w] = xk_s;
    }
#pragma unroll
    for (int et = 0; et < 2; ++et) { xEc[et] = xEn[et]; xwEc[et] = xwEn[et]; }
    __syncthreads();  // the only per-step barrier
  }

  // ---- final lam (per-lane) + emit ----
  const int fb = nAct & 1;
  float lmF0, lmF1 = 0.0f;
  {
    f32x4 qa = *(const f32x4*)&sRed[fb][0][n][0];
    f32x4 qb = *(const f32x4*)&sRed[fb][0][n][4];
    f32x4 qs = qa + qb;
    lmF0 = rsqrtf(fmaxf((qs[0] + qs[1]) + (qs[2] + qs[3]), 1e-12f));
  }
  if (n < 4) {
    f32x4 qa = *(const f32x4*)&sRed[fb][0][16 + n][0];
    f32x4 qb = *(const f32x4*)&sRed[fb][0][16 + n][4];
    f32x4 qs = qa + qb;
    lmF1 = rsqrtf(fmaxf((qs[0] + qs[1]) + (qs[2] + qs[3]), 1e-12f));
  }
#pragma unroll
  for (int et = 0; et < 2; ++et) {
    const int e0 = e0a + 16 * et;
    {
      f32x4 o;
#pragma unroll
      for (int r = 0; r < 4; ++r) o[r] = lmF0 * hReg[et][0][r];
      *(f32x4*)&out[(size_t)(b * K_ + n) * D_ + e0] = o;
    }
    if (n < 4) {
      f32x4 o;
#pragma unroll
      for (int r = 0; r < 4; ++r) o[r] = lmF1 * hReg[et][1][r];
      *(f32x4*)&out[(size_t)(b * K_ + 16 + n) * D_ + e0] = o;
    }
  }
}

extern "C" void kernel_launch(void* const* d_in, const int* in_sizes, int n_in,
                              void* d_out, int out_size, void* d_ws, size_t ws_size,
                              hipStream_t stream) {
  const float* es   = (const float*)d_in[0];
  const int*   mask = (const int*)d_in[1];
  const float* keys = (const float*)d_in[2];
  const float* U    = (const float*)d_in[3];
  const float* V    = (const float*)d_in[4];
  const float* W    = (const float*)d_in[5];
  float* out = (float*)d_out;
  float* XWc = (float*)d_ws;  // compact per-block XW: 256 x 512 x 1KB = 128 MiB
  rnn_fused11<<<B_, NT, 0, stream>>>(es, mask, keys, U, V, W, XWc, out);
}

// Round 6
// 676.567 us; speedup vs baseline: 1.0663x; 1.0108x over previous
//
#include <hip/hip_runtime.h>
#include <math.h>

#define B_ 256
#define S_ 512
#define K_ 20
#define D_ 256
#define NT 512
#define LDH 264   // LDS row stride (shorts), 16B-aligned rows, bank-spread

typedef __attribute__((ext_vector_type(8))) short short8;
typedef __attribute__((ext_vector_type(4))) float f32x4;
typedef __attribute__((ext_vector_type(8))) _Float16 half8;
typedef __attribute__((ext_vector_type(2))) __fp16 fp16x2;   // cvt_pkrtz result type
typedef __attribute__((ext_vector_type(2))) unsigned int uint2v;

__device__ __forceinline__ unsigned short rne_bf16(float f) {
  unsigned u = __builtin_bit_cast(unsigned, f);
  u += 0x7FFFu + ((u >> 16) & 1u);
  return (unsigned short)(u >> 16);
}
__device__ __forceinline__ float bf16_to_f32(unsigned short h) {
  return __builtin_bit_cast(float, ((unsigned)h) << 16);
}
__device__ __forceinline__ unsigned pk_f16(float a, float b) {
  fp16x2 p = __builtin_amdgcn_cvt_pkrtz(a, b);  // v_cvt_pkrtz_f16_f32
  return __builtin_bit_cast(unsigned, p);
}

// rnn_fused12: XK = es_act @ keys^T precomputed in prologue (MFMA pre-pass,
// reuses aHi/aLo regs; wave0-only) -> sXK in LDS. Loop loses the pxk channel
// (16 fma + 1/3 reduce + 1/3 sRed). sRed rows padded 12->13 floats (bank fix).
__global__ __launch_bounds__(NT, 2)
void rnn_fused12(const float* __restrict__ es, const int* __restrict__ mask,
                 const float* __restrict__ keys, const float* __restrict__ U,
                 const float* __restrict__ V, const float* __restrict__ W,
                 float* __restrict__ XWc, float* __restrict__ out) {
  __shared__ unsigned short sH0[32 * LDH];  // state buf 0 (prologue: hi staging)
  __shared__ unsigned short sH1[32 * LDH];  // state buf 1 (prologue: lo staging)
  __shared__ float sRed[2][2][32][13];      // [buf][psq/pxh][k-row][wave + pad(13: gcd(13,32)=1)]
  __shared__ float sXK[512 * 20 + 16];      // precomputed x_i . keys (pad: kk<=31 overread)
  __shared__ short sAct[S_];
  __shared__ int   sNact;

  const int b = blockIdx.x, t = threadIdx.x;
  const int w = t >> 6, lane = t & 63, quad = lane >> 4, n = lane & 15;
  const int e0a = (w << 5) + quad * 4;

  // ---- P0: zero sRed (rows 20..31 stay 0 forever); compact active list ----
  for (int i = t; i < 2 * 2 * 32 * 13; i += NT) ((float*)sRed)[i] = 0.0f;
  if (w == 0) {
    int base = 0;
    for (int c = 0; c < 8; ++c) {
      int s = c * 64 + lane;
      int mv = mask[b * S_ + s];
      unsigned long long bal = __ballot(mv != 0);
      int pos = base + (int)__popcll(bal & ((1ull << lane) - 1ull));
      if (mv) sAct[pos] = (short)s;
      base += (int)__popcll(bal);
    }
    if (lane == 0) sNact = base;
  }
  __syncthreads();
  const int nAct = sNact;

  short8 aHi[8][2], aLo[8][2];  // split-bf16 A-frags (keys, then W, then V)
  auto load_A = [&](const float* __restrict__ M) {
#pragma unroll
    for (int kt = 0; kt < 8; ++kt)
#pragma unroll
      for (int et = 0; et < 2; ++et) {
        const int e = ((2 * w + et) << 4) + n;
        const int d0 = kt * 32 + quad * 8;
        short8 h8, l8;
#pragma unroll
        for (int j = 0; j < 8; ++j) {
          float f = M[(d0 + j) * D_ + e];
          unsigned short hi = rne_bf16(f);
          h8[j] = (short)hi;
          l8[j] = (short)rne_bf16(f - bf16_to_f32(hi));
        }
        aHi[kt][et] = h8; aLo[kt][et] = l8;
      }
  };
  // keys as A: A[row=k][d] = keys[k][d]; rows >= 20 (all waves > 0) are zero.
  auto load_A_keys = [&]() {
#pragma unroll
    for (int kt = 0; kt < 8; ++kt)
#pragma unroll
      for (int et = 0; et < 2; ++et) {
        const int kk2 = ((2 * w + et) << 4) + n;
        const int d0 = kt * 32 + quad * 8;
        short8 h8 = {}, l8 = {};
        if (kk2 < K_) {
#pragma unroll
          for (int j = 0; j < 8; ++j) {
            float f = keys[(size_t)(b * K_ + kk2) * D_ + d0 + j];
            unsigned short hi = rne_bf16(f);
            h8[j] = (short)hi;
            l8[j] = (short)rne_bf16(f - bf16_to_f32(hi));
          }
        }
        aHi[kt][et] = h8; aLo[kt][et] = l8;
      }
  };
  auto run_mfma3 = [&](f32x4 acc[2][2]) {  // split-bf16 3-product (hi sH0, lo sH1)
#pragma unroll
    for (int kt = 0; kt < 8; ++kt) {
      short8 bhi[2], blo[2];
#pragma unroll
      for (int ke = 0; ke < 2; ++ke) {
        const int off = (ke * 16 + n) * LDH + kt * 32 + quad * 8;
        bhi[ke] = *(const short8*)&sH0[off];
        blo[ke] = *(const short8*)&sH1[off];
      }
#pragma unroll
      for (int et = 0; et < 2; ++et)
#pragma unroll
        for (int ke = 0; ke < 2; ++ke) {
          acc[et][ke] = __builtin_amdgcn_mfma_f32_16x16x32_bf16(aHi[kt][et], bhi[ke], acc[et][ke], 0, 0, 0);
          acc[et][ke] = __builtin_amdgcn_mfma_f32_16x16x32_bf16(aLo[kt][et], bhi[ke], acc[et][ke], 0, 0, 0);
          acc[et][ke] = __builtin_amdgcn_mfma_f32_16x16x32_bf16(aHi[kt][et], blo[ke], acc[et][ke], 0, 0, 0);
        }
    }
  };
  // stage 32 gathered es rows (pass p), split-bf16
  auto stage_rows = [&](int p) {
    const int rr = t >> 4, c0 = (t & 15) * 16;
    const int ridx = p * 32 + rr;
    const int sidx = sAct[(ridx < nAct) ? ridx : (nAct - 1)];
    const float* src = es + ((size_t)b * S_ + sidx) * D_ + c0;
#pragma unroll
    for (int h2 = 0; h2 < 2; ++h2) {
      f32x4 f0 = *(const f32x4*)(src + h2 * 8);
      f32x4 f1 = *(const f32x4*)(src + h2 * 8 + 4);
      short8 hh, ll;
#pragma unroll
      for (int j = 0; j < 4; ++j) {
        unsigned short a = rne_bf16(f0[j]);
        hh[j] = (short)a; ll[j] = (short)rne_bf16(f0[j] - bf16_to_f32(a));
        unsigned short bq = rne_bf16(f1[j]);
        hh[4 + j] = (short)bq; ll[4 + j] = (short)rne_bf16(f1[j] - bf16_to_f32(bq));
      }
      *(short8*)&sH0[rr * LDH + c0 + h2 * 8] = hh;
      *(short8*)&sH1[rr * LDH + c0 + h2 * 8] = ll;
    }
  };

  const size_t bbase = (size_t)b * S_;
  const int nPass = (nAct + 31) >> 5;

  // ---- Phase XK: sXK[g][k] = es_act[g] . keys[k] (wave0-only MFMA) ----
  if (nAct > 0) {
    load_A_keys();
    for (int p = 0; p < nPass; ++p) {
      stage_rows(p);
      __syncthreads();
      if (w == 0) {
        f32x4 axk[2][2] = {};
        run_mfma3(axk);
        // out[k = et*16 + quad*4 + r][row = p*32 + ke*16 + n]
#pragma unroll
        for (int et = 0; et < 2; ++et) {
          const int kb = et * 16 + quad * 4;
          if (kb < K_) {
#pragma unroll
            for (int ke = 0; ke < 2; ++ke) {
              const int row = p * 32 + ke * 16 + n;
              *(f32x4*)&sXK[row * 20 + kb] = axk[et][ke];
            }
          }
        }
      }
      __syncthreads();
    }
  }

  // ---- Phase XW: compact x@W for this batch's active rows -> scratch ----
  if (nAct > 0) {
    load_A(W);
    for (int p = 0; p < nPass; ++p) {
      stage_rows(p);
      __syncthreads();
      f32x4 acc[2][2] = {};
      run_mfma3(acc);
#pragma unroll
      for (int et = 0; et < 2; ++et)
#pragma unroll
        for (int ke = 0; ke < 2; ++ke) {
          const int g = p * 32 + ke * 16 + n;
          if (g < nAct)
            *(f32x4*)&XWc[(bbase + g) * D_ + e0a + 16 * et] = acc[et][ke];
        }
      __syncthreads();
    }
  }

  // ---- zero BOTH buffers fully (rows 20..31 + pads stay 0 afterwards) ----
  for (int i = t; i < 32 * LDH; i += NT) { sH0[i] = 0; sH1[i] = 0; }
  __syncthreads();

  // ---- keys staging (split-bf16) + V frags ----
  for (int i = t; i < K_ * D_; i += NT) {
    int k = i >> 8, d = i & 255;
    float f = keys[(b * K_ + k) * D_ + d];
    unsigned short hi = rne_bf16(f);
    sH0[k * LDH + d] = hi;
    sH1[k * LDH + d] = rne_bf16(f - bf16_to_f32(hi));
  }
  load_A(V);
  __syncthreads();

  f32x4 kvReg[2][2] = {};
  run_mfma3(kvReg);
  __syncthreads();  // kV reads done

  // ---- zero state rows (both buffers); load U as fp16 frags ----
  for (int i = t; i < K_ * LDH; i += NT) { sH0[i] = 0; sH1[i] = 0; }
  short8 aU[8][2];  // fp16 U^T frags (single product in the loop)
#pragma unroll
  for (int kt = 0; kt < 8; ++kt)
#pragma unroll
    for (int et = 0; et < 2; ++et) {
      const int e = ((2 * w + et) << 4) + n;
      const int d0 = kt * 32 + quad * 8;
      short8 h8;
#pragma unroll
      for (int j = 0; j < 8; ++j)
        h8[j] = (short)__builtin_bit_cast(unsigned short, (_Float16)U[(d0 + j) * D_ + e]);
      aU[kt][et] = h8;
    }
  // fp16 MFMA; ke=1 B rows 20..31 are permanently zero -> only n<4 lanes read.
  auto run_mfma1 = [&](f32x4 acc[2][2], const unsigned short* __restrict__ bp) {
#pragma unroll
    for (int kt = 0; kt < 8; ++kt) {
      const int co = kt * 32 + quad * 8;
      short8 b0 = *(const short8*)&bp[n * LDH + co];
      short8 b1 = {};
      if (n < 4) b1 = *(const short8*)&bp[(16 + n) * LDH + co];
      half8 q0 = __builtin_bit_cast(half8, b0);
      half8 q1 = __builtin_bit_cast(half8, b1);
#pragma unroll
      for (int et = 0; et < 2; ++et) {
        half8 aq = __builtin_bit_cast(half8, aU[kt][et]);
        acc[et][0] = __builtin_amdgcn_mfma_f32_16x16x32_f16(aq, q0, acc[et][0], 0, 0, 0);
        acc[et][1] = __builtin_amdgcn_mfma_f32_16x16x32_f16(aq, q1, acc[et][1], 0, 0, 0);
      }
    }
  };

  f32x4 hReg[2][2] = {};
  f32x4 xEc[2] = {}, xwEc[2] = {};
  if (nAct > 0) {
    const int s1 = sAct[(nAct > 1) ? 1 : 0];
#pragma unroll
    for (int et = 0; et < 2; ++et) {
      xEc[et]  = *(const f32x4*)&es[((size_t)b * S_ + s1) * D_ + e0a + 16 * et];
      xwEc[et] = *(const f32x4*)&XWc[bbase * D_ + e0a + 16 * et];
    }
  }
  __syncthreads();  // ready for step 0 (sRed zeros = correct h0=0 seed)

  // cross-half swap on VALU pipe
  auto xswap = [](float& a, float& b) {
    asm("v_permlane32_swap_b32 %0, %1" : "+v"(a), "+v"(b));
  };

  // ---- recurrence: one barrier per step ----
  for (int i = 0; i < nAct; ++i) {
    const int rb = i & 1, wbuf = rb ^ 1;
    const unsigned short* bR = rb ? sH1 : sH0;
    unsigned short* bW = rb ? sH0 : sH1;

    // next-slot global loads (consumed in epilogue of step i+1)
    const int iX = (i + 2 < nAct) ? i + 2 : nAct - 1;
    const int iW = (i + 1 < nAct) ? i + 1 : nAct - 1;
    const size_t rX = ((size_t)b * S_ + sAct[iX]) * D_;
    f32x4 xEn[2], xwEn[2];
#pragma unroll
    for (int et = 0; et < 2; ++et) {
      xEn[et]  = *(const f32x4*)&es[rX + e0a + 16 * et];
      xwEn[et] = *(const f32x4*)&XWc[(bbase + iW) * D_ + e0a + 16 * et];
    }

    // single-stream per-lane lam/g: lane computes k = lane&31.
    // rows 20..31 of sRed are zero; sXK overread (kk>=20) is finite garbage
    float lmv, gv;
    {
      const int kk = lane & 31;
      f32x4 qa = *(const f32x4*)&sRed[rb][0][kk][0];
      f32x4 qb = *(const f32x4*)&sRed[rb][0][kk][4];
      f32x4 ha = *(const f32x4*)&sRed[rb][1][kk][0];
      f32x4 hb = *(const f32x4*)&sRed[rb][1][kk][4];
      const float xk = sXK[i * 20 + kk];
      f32x4 qs = qa + qb, hs = ha + hb;
      float ss = (qs[0] + qs[1]) + (qs[2] + qs[3]);
      float xh = (hs[0] + hs[1]) + (hs[2] + hs[3]);
      lmv = rsqrtf(fmaxf(ss, 1e-12f));
      gv = __fdividef(1.0f, 1.0f + __expf(-fmaf(lmv, xh, xk)));
    }
    // static swizzle broadcasts (pull within each 32-half)
    const float lm0 = __builtin_bit_cast(float, __builtin_amdgcn_ds_swizzle(__builtin_bit_cast(int, lmv), 0x000F));
    const float g0  = __builtin_bit_cast(float, __builtin_amdgcn_ds_swizzle(__builtin_bit_cast(int, gv),  0x000F));
    const float lm1s = __builtin_bit_cast(float, __builtin_amdgcn_ds_swizzle(__builtin_bit_cast(int, lmv), 0x0203));
    const float g1s  = __builtin_bit_cast(float, __builtin_amdgcn_ds_swizzle(__builtin_bit_cast(int, gv),  0x0203));
    // zero on n>=4: keeps ke=1 dead lanes' u == 0 (garbage containment)
    const float lm1 = (n < 4) ? lm1s : 0.0f;
    const float g1 = (n < 4) ? g1s : 0.0f;

    f32x4 acc[2][2] = {};
    run_mfma1(acc, bR);

    float psq0 = 0.0f, psq1 = 0.0f, pxh0 = 0.0f, pxh1 = 0.0f;
#pragma unroll
    for (int et = 0; et < 2; ++et) {
      const int e0 = e0a + 16 * et;
      f32x4 xw4 = xwEc[et];
      f32x4 xn4 = xEc[et];
      {  // ke=0
        f32x4 u;
#pragma unroll
        for (int r = 0; r < 4; ++r) {
          float T = fmaxf(fmaf(lm0, acc[et][0][r], kvReg[et][0][r] + xw4[r]), 0.0f);
          float uv = fmaf(g0, T, lm0 * hReg[et][0][r]);
          u[r] = uv;
          psq0 = fmaf(uv, uv, psq0);
          pxh0 = fmaf(xn4[r], uv, pxh0);
        }
        hReg[et][0] = u;
        uint2v hh;
        hh[0] = pk_f16(u[0], u[1]);
        hh[1] = pk_f16(u[2], u[3]);
        *(uint2v*)&bW[n * LDH + e0] = hh;
      }
      {  // ke=1
        f32x4 u;
#pragma unroll
        for (int r = 0; r < 4; ++r) {
          float T = fmaxf(fmaf(lm1, acc[et][1][r], kvReg[et][1][r] + xw4[r]), 0.0f);
          float uv = fmaf(g1, T, lm1 * hReg[et][1][r]);
          u[r] = uv;
          psq1 = fmaf(uv, uv, psq1);
          pxh1 = fmaf(xn4[r], uv, pxh1);
        }
        hReg[et][1] = u;
        if (n < 4) {
          uint2v hh;
          hh[0] = pk_f16(u[0], u[1]);
          hh[1] = pk_f16(u[2], u[3]);
          *(uint2v*)&bW[(16 + n) * LDH + e0] = hh;
        }
      }
    }
    // quad-pair reduce (LDS swizzle) + cross-half on VALU via permlane swap
    psq0 += __shfl_xor(psq0, 16, 64); psq1 += __shfl_xor(psq1, 16, 64);
    pxh0 += __shfl_xor(pxh0, 16, 64); pxh1 += __shfl_xor(pxh1, 16, 64);
    xswap(psq0, psq1); const float sq_s = psq0 + psq1;
    xswap(pxh0, pxh1); const float xh_s = pxh0 + pxh1;
    if (quad == 0) {  // lanes 0..15: totals for k = n
      sRed[wbuf][0][n][w] = sq_s; sRed[wbuf][1][n][w] = xh_s;
    }
    if (quad == 2 && n < 4) {  // lanes 32..35: totals for k = 16+n
      sRed[wbuf][0][16 + n][w] = sq_s; sRed[wbuf][1][16 + n][w] = xh_s;
    }
#pragma unroll
    for (int et = 0; et < 2; ++et) { xEc[et] = xEn[et]; xwEc[et] = xwEn[et]; }
    __syncthreads();  // the only per-step barrier
  }

  // ---- final lam (per-lane) + emit ----
  const int fb = nAct & 1;
  float lmF0, lmF1 = 0.0f;
  {
    f32x4 qa = *(const f32x4*)&sRed[fb][0][n][0];
    f32x4 qb = *(const f32x4*)&sRed[fb][0][n][4];
    f32x4 qs = qa + qb;
    lmF0 = rsqrtf(fmaxf((qs[0] + qs[1]) + (qs[2] + qs[3]), 1e-12f));
  }
  if (n < 4) {
    f32x4 qa = *(const f32x4*)&sRed[fb][0][16 + n][0];
    f32x4 qb = *(const f32x4*)&sRed[fb][0][16 + n][4];
    f32x4 qs = qa + qb;
    lmF1 = rsqrtf(fmaxf((qs[0] + qs[1]) + (qs[2] + qs[3]), 1e-12f));
  }
#pragma unroll
  for (int et = 0; et < 2; ++et) {
    const int e0 = e0a + 16 * et;
    {
      f32x4 o;
#pragma unroll
      for (int r = 0; r < 4; ++r) o[r] = lmF0 * hReg[et][0][r];
      *(f32x4*)&out[(size_t)(b * K_ + n) * D_ + e0] = o;
    }
    if (n < 4) {
      f32x4 o;
#pragma unroll
      for (int r = 0; r < 4; ++r) o[r] = lmF1 * hReg[et][1][r];
      *(f32x4*)&out[(size_t)(b * K_ + 16 + n) * D_ + e0] = o;
    }
  }
}

extern "C" void kernel_launch(void* const* d_in, const int* in_sizes, int n_in,
                              void* d_out, int out_size, void* d_ws, size_t ws_size,
                              hipStream_t stream) {
  const float* es   = (const float*)d_in[0];
  const int*   mask = (const int*)d_in[1];
  const float* keys = (const float*)d_in[2];
  const float* U    = (const float*)d_in[3];
  const float* V    = (const float*)d_in[4];
  const float* W    = (const float*)d_in[5];
  float* out = (float*)d_out;
  float* XWc = (float*)d_ws;  // compact per-block XW: 256 x 512 x 1KB = 128 MiB
  rnn_fused12<<<B_, NT, 0, stream>>>(es, mask, keys, U, V, W, XWc, out);
}